// Round 1
// baseline (1151.405 us; speedup 1.0000x reference)
//
#include <hip/hip_runtime.h>

#define N_NODES 50000

// ---------------- CSR build ----------------

__global__ void k_hist(const int* __restrict__ dst, int* __restrict__ cnt, int E) {
  int t = blockIdx.x * blockDim.x + threadIdx.x;
  if (t < E) atomicAdd(&cnt[dst[t]], 1);
}

__global__ void k_scan(const int* __restrict__ cnt, int* __restrict__ offs,
                       int* __restrict__ cursor, int n) {
  __shared__ int part[1024];
  const int tid = threadIdx.x;
  const int C = (n + 1023) >> 10;
  const int beg = tid * C;
  const int end = min(beg + C, n);
  int s = 0;
  for (int i = beg; i < end; ++i) s += cnt[i];
  part[tid] = s;
  __syncthreads();
  for (int d = 1; d < 1024; d <<= 1) {
    int v = (tid >= d) ? part[tid - d] : 0;
    __syncthreads();
    part[tid] += v;
    __syncthreads();
  }
  int run = (tid == 0) ? 0 : part[tid - 1];
  for (int i = beg; i < end; ++i) {
    offs[i] = run; cursor[i] = run; run += cnt[i];
  }
  if (tid == (n - 1) / C) offs[n] = run;
}

__global__ void k_fill(const int* __restrict__ src, const int* __restrict__ dst,
                       int* __restrict__ cursor, int* __restrict__ nbr, int E) {
  int t = blockIdx.x * blockDim.x + threadIdx.x;
  if (t < E) {
    int p = atomicAdd(&cursor[dst[t]], 1);
    nbr[p] = src[t];
  }
}

// ---------------- mean aggregation (gather) ----------------
// one wave per node; lane owns dims 2*lane, 2*lane+1

__global__ void k_agg(const float* __restrict__ x, const int* __restrict__ offs,
                      const int* __restrict__ nbr, float* __restrict__ agg, int n) {
  const int lane = threadIdx.x & 63;
  const int w = (int)((blockIdx.x * blockDim.x + threadIdx.x) >> 6);
  const int nw = (int)((gridDim.x * blockDim.x) >> 6);
  for (int node = w; node < n; node += nw) {
    const int beg = offs[node], end = offs[node + 1];
    float ax0 = 0.f, ay0 = 0.f, ax1 = 0.f, ay1 = 0.f;
    int j = beg;
    for (; j + 2 <= end; j += 2) {
      int s0 = nbr[j], s1 = nbr[j + 1];
      float2 v0 = *(const float2*)(x + (size_t)s0 * 128 + lane * 2);
      float2 v1 = *(const float2*)(x + (size_t)s1 * 128 + lane * 2);
      ax0 += v0.x; ay0 += v0.y; ax1 += v1.x; ay1 += v1.y;
    }
    if (j < end) {
      int s0 = nbr[j];
      float2 v0 = *(const float2*)(x + (size_t)s0 * 128 + lane * 2);
      ax0 += v0.x; ay0 += v0.y;
    }
    float inv = 1.0f / (float)max(end - beg, 1);
    float2 o; o.x = (ax0 + ax1) * inv; o.y = (ay0 + ay1) * inv;
    *(float2*)(agg + (size_t)node * 128 + lane * 2) = o;
  }
}

// ---------------- fused SAGE linear: h = relu([agg, xin] @ [Wl;Wr] + b) ----------------
// full weight (256x128 f32 = 128KB) in LDS; 1 block/CU; wave computes 4 rows x 128 cols

__global__ __launch_bounds__(256, 1)
void k_linear(const float* __restrict__ agg, const float* __restrict__ xin,
              const float* __restrict__ Wl, const float* __restrict__ Wr,
              const float* __restrict__ bias, float* __restrict__ hout, int M) {
  __shared__ float Wlds[256 * 128];
  __shared__ float rb[16][256];
  __shared__ float blds[128];
  const int tid = threadIdx.x;
  for (int i = tid; i < 8192; i += 256) {
    int f = i * 4;
    float4 v = (f < 16384) ? *(const float4*)(Wl + f)
                           : *(const float4*)(Wr + (f - 16384));
    *(float4*)(&Wlds[f]) = v;
  }
  if (tid < 128) blds[tid] = bias[tid];
  __syncthreads();
  const int lane = tid & 63;
  const int w = tid >> 6;
  for (int base = blockIdx.x * 16; base < M; base += gridDim.x * 16) {
    __syncthreads();
    for (int i = tid; i < 1024; i += 256) {
      int row = i >> 6, q = i & 63;
      int rg = base + row;
      float4 v = make_float4(0.f, 0.f, 0.f, 0.f);
      if (rg < M) {
        v = (q < 32) ? *(const float4*)(agg + (size_t)rg * 128 + q * 4)
                     : *(const float4*)(xin + (size_t)rg * 128 + (q - 32) * 4);
      }
      int col = (q < 32) ? q * 4 : 128 + (q - 32) * 4;
      *(float4*)(&rb[row][col]) = v;
    }
    __syncthreads();
    float acc[4][2];
    #pragma unroll
    for (int i = 0; i < 4; ++i) { acc[i][0] = 0.f; acc[i][1] = 0.f; }
    const float* r0 = rb[4 * w + 0];
    const float* r1 = rb[4 * w + 1];
    const float* r2 = rb[4 * w + 2];
    const float* r3 = rb[4 * w + 3];
    for (int k = 0; k < 256; k += 4) {
      float4 a0 = *(const float4*)(r0 + k);
      float4 a1 = *(const float4*)(r1 + k);
      float4 a2 = *(const float4*)(r2 + k);
      float4 a3 = *(const float4*)(r3 + k);
      #pragma unroll
      for (int kk = 0; kk < 4; ++kk) {
        float2 wv = *(const float2*)(&Wlds[(k + kk) * 128 + (lane << 1)]);
        float e0 = ((const float*)&a0)[kk];
        float e1 = ((const float*)&a1)[kk];
        float e2 = ((const float*)&a2)[kk];
        float e3 = ((const float*)&a3)[kk];
        acc[0][0] += e0 * wv.x; acc[0][1] += e0 * wv.y;
        acc[1][0] += e1 * wv.x; acc[1][1] += e1 * wv.y;
        acc[2][0] += e2 * wv.x; acc[2][1] += e2 * wv.y;
        acc[3][0] += e3 * wv.x; acc[3][1] += e3 * wv.y;
      }
    }
    #pragma unroll
    for (int i = 0; i < 4; ++i) {
      int rg = base + 4 * w + i;
      if (rg < M) {
        float2 o;
        o.x = fmaxf(acc[i][0] + blds[lane * 2], 0.f);
        o.y = fmaxf(acc[i][1] + blds[lane * 2 + 1], 0.f);
        *(float2*)(&hout[(size_t)rg * 128 + lane * 2]) = o;
      }
    }
  }
}

// ---------------- classifier: out = relu([h2[bs],h2[bd],feat] @ Wc1 + bc1) @ Wc2 + bc2 ----------------

__global__ __launch_bounds__(256, 1)
void k_cls(const float* __restrict__ h2, const int* __restrict__ bs,
           const int* __restrict__ bd, const float* __restrict__ feat,
           const float* __restrict__ Wc1, const float* __restrict__ bc1,
           const float* __restrict__ Wc2, const float* __restrict__ bc2,
           float* __restrict__ out, int M) {
  __shared__ float Wlds[288 * 128];
  __shared__ float rb[8][288];
  __shared__ float b1lds[128];
  __shared__ float w2lds[128];
  const int tid = threadIdx.x;
  for (int i = tid; i < 9216; i += 256) {
    *(float4*)(&Wlds[i * 4]) = *(const float4*)(Wc1 + i * 4);
  }
  if (tid < 128) { b1lds[tid] = bc1[tid]; w2lds[tid] = Wc2[tid]; }
  const float bc2v = bc2[0];
  __syncthreads();
  const int lane = tid & 63;
  const int w = tid >> 6;
  for (int base = blockIdx.x * 8; base < M; base += gridDim.x * 8) {
    __syncthreads();
    for (int i = tid; i < 576; i += 256) {
      int row = i / 72, q = i % 72;
      int rg = base + row;
      float4 v;
      int col;
      if (q < 32)      { v = *(const float4*)(h2 + (size_t)bs[rg] * 128 + q * 4); col = q * 4; }
      else if (q < 64) { v = *(const float4*)(h2 + (size_t)bd[rg] * 128 + (q - 32) * 4); col = 128 + (q - 32) * 4; }
      else             { v = *(const float4*)(feat + (size_t)rg * 32 + (q - 64) * 4); col = 256 + (q - 64) * 4; }
      *(float4*)(&rb[row][col]) = v;
    }
    __syncthreads();
    float acc00 = 0.f, acc01 = 0.f, acc10 = 0.f, acc11 = 0.f;
    const float* r0 = rb[2 * w + 0];
    const float* r1 = rb[2 * w + 1];
    for (int k = 0; k < 288; k += 4) {
      float4 a0 = *(const float4*)(r0 + k);
      float4 a1 = *(const float4*)(r1 + k);
      #pragma unroll
      for (int kk = 0; kk < 4; ++kk) {
        float2 wv = *(const float2*)(&Wlds[(k + kk) * 128 + (lane << 1)]);
        float e0 = ((const float*)&a0)[kk];
        float e1 = ((const float*)&a1)[kk];
        acc00 += e0 * wv.x; acc01 += e0 * wv.y;
        acc10 += e1 * wv.x; acc11 += e1 * wv.y;
      }
    }
    float z00 = fmaxf(acc00 + b1lds[lane * 2], 0.f);
    float z01 = fmaxf(acc01 + b1lds[lane * 2 + 1], 0.f);
    float z10 = fmaxf(acc10 + b1lds[lane * 2], 0.f);
    float z11 = fmaxf(acc11 + b1lds[lane * 2 + 1], 0.f);
    float p0 = z00 * w2lds[lane * 2] + z01 * w2lds[lane * 2 + 1];
    float p1 = z10 * w2lds[lane * 2] + z11 * w2lds[lane * 2 + 1];
    #pragma unroll
    for (int d = 32; d >= 1; d >>= 1) {
      p0 += __shfl_xor(p0, d);
      p1 += __shfl_xor(p1, d);
    }
    if (lane == 0) {
      out[base + 2 * w]     = p0 + bc2v;
      out[base + 2 * w + 1] = p1 + bc2v;
    }
  }
}

// ---------------- launcher ----------------

extern "C" void kernel_launch(void* const* d_in, const int* in_sizes, int n_in,
                              void* d_out, int out_size, void* d_ws, size_t ws_size,
                              hipStream_t stream) {
  const float* x    = (const float*)d_in[0];
  const int*   ei   = (const int*)d_in[1];
  const int*   bei  = (const int*)d_in[2];
  const float* feat = (const float*)d_in[3];
  const float* W1l  = (const float*)d_in[4];
  const float* b1   = (const float*)d_in[5];
  const float* W1r  = (const float*)d_in[6];
  const float* W2l  = (const float*)d_in[7];
  const float* b2   = (const float*)d_in[8];
  const float* W2r  = (const float*)d_in[9];
  const float* Wc1  = (const float*)d_in[10];
  const float* bc1  = (const float*)d_in[11];
  const float* Wc2  = (const float*)d_in[12];
  const float* bc2  = (const float*)d_in[13];
  float* out = (float*)d_out;

  const int E  = in_sizes[1] / 2;   // 800000
  const int EB = in_sizes[2] / 2;   // 200000
  const int* src = ei;
  const int* dst = ei + E;
  const int* bs = bei;
  const int* bd = bei + EB;

  char* ws = (char*)d_ws;
  int*   cnt    = (int*)(ws + 0);
  int*   offs   = (int*)(ws + (256u << 10));
  int*   cursor = (int*)(ws + (512u << 10));
  int*   nbr    = (int*)(ws + (768u << 10));              // E ints = 3.2MB
  float* agg    = (float*)(ws + (8ull << 20));            // 25.6MB
  float* h1     = (float*)(ws + (40ull << 20));           // 25.6MB
  float* h2     = (float*)(ws + (72ull << 20));           // 25.6MB

  hipMemsetAsync(cnt, 0, N_NODES * sizeof(int), stream);

  const int eb = (E + 255) / 256;
  k_hist<<<eb, 256, 0, stream>>>(dst, cnt, E);
  k_scan<<<1, 1024, 0, stream>>>(cnt, offs, cursor, N_NODES);
  k_fill<<<eb, 256, 0, stream>>>(src, dst, cursor, nbr, E);

  // layer 1
  k_agg<<<2048, 256, 0, stream>>>(x, offs, nbr, agg, N_NODES);
  k_linear<<<256, 256, 0, stream>>>(agg, x, W1l, W1r, b1, h1, N_NODES);
  // layer 2
  k_agg<<<2048, 256, 0, stream>>>(h1, offs, nbr, agg, N_NODES);
  k_linear<<<256, 256, 0, stream>>>(agg, h1, W2l, W2r, b2, h2, N_NODES);
  // classifier
  k_cls<<<256, 256, 0, stream>>>(h2, bs, bd, feat, Wc1, bc1, Wc2, bc2, out, EB);
}

// Round 2
// 903.756 us; speedup vs baseline: 1.2740x; 1.2740x over previous
//
#include <hip/hip_runtime.h>

#define N_NODES 50000

// ---------------- CSR build ----------------

__global__ void k_hist(const int* __restrict__ dst, int* __restrict__ cnt, int E) {
  int t = blockIdx.x * blockDim.x + threadIdx.x;
  if (t < E) atomicAdd(&cnt[dst[t]], 1);
}

__global__ void k_scan(const int* __restrict__ cnt, int* __restrict__ offs,
                       int* __restrict__ cursor, int n) {
  __shared__ int part[1024];
  const int tid = threadIdx.x;
  const int C = (n + 1023) >> 10;
  const int beg = tid * C;
  const int end = min(beg + C, n);
  int s = 0;
  for (int i = beg; i < end; ++i) s += cnt[i];
  part[tid] = s;
  __syncthreads();
  for (int d = 1; d < 1024; d <<= 1) {
    int v = (tid >= d) ? part[tid - d] : 0;
    __syncthreads();
    part[tid] += v;
    __syncthreads();
  }
  int run = (tid == 0) ? 0 : part[tid - 1];
  for (int i = beg; i < end; ++i) {
    offs[i] = run; cursor[i] = run; run += cnt[i];
  }
  if (tid == (n - 1) / C) offs[n] = run;
}

__global__ void k_fill(const int* __restrict__ src, const int* __restrict__ dst,
                       int* __restrict__ cursor, int* __restrict__ nbr, int E) {
  int t = blockIdx.x * blockDim.x + threadIdx.x;
  if (t < E) {
    int p = atomicAdd(&cursor[dst[t]], 1);
    nbr[p] = src[t];
  }
}

// ---------------- mean aggregation (gather) ----------------
// one wave per node; lane owns dims 2*lane, 2*lane+1

__global__ void k_agg(const float* __restrict__ x, const int* __restrict__ offs,
                      const int* __restrict__ nbr, float* __restrict__ agg, int n) {
  const int lane = threadIdx.x & 63;
  const int w = (int)((blockIdx.x * blockDim.x + threadIdx.x) >> 6);
  const int nw = (int)((gridDim.x * blockDim.x) >> 6);
  for (int node = w; node < n; node += nw) {
    const int beg = offs[node], end = offs[node + 1];
    float a0x = 0.f, a0y = 0.f, a1x = 0.f, a1y = 0.f;
    float a2x = 0.f, a2y = 0.f, a3x = 0.f, a3y = 0.f;
    int j = beg;
    for (; j + 4 <= end; j += 4) {
      int s0 = __builtin_amdgcn_readfirstlane(nbr[j]);
      int s1 = __builtin_amdgcn_readfirstlane(nbr[j + 1]);
      int s2 = __builtin_amdgcn_readfirstlane(nbr[j + 2]);
      int s3 = __builtin_amdgcn_readfirstlane(nbr[j + 3]);
      float2 v0 = *(const float2*)(x + (size_t)s0 * 128 + lane * 2);
      float2 v1 = *(const float2*)(x + (size_t)s1 * 128 + lane * 2);
      float2 v2 = *(const float2*)(x + (size_t)s2 * 128 + lane * 2);
      float2 v3 = *(const float2*)(x + (size_t)s3 * 128 + lane * 2);
      a0x += v0.x; a0y += v0.y; a1x += v1.x; a1y += v1.y;
      a2x += v2.x; a2y += v2.y; a3x += v3.x; a3y += v3.y;
    }
    for (; j < end; ++j) {
      int s0 = __builtin_amdgcn_readfirstlane(nbr[j]);
      float2 v0 = *(const float2*)(x + (size_t)s0 * 128 + lane * 2);
      a0x += v0.x; a0y += v0.y;
    }
    float inv = 1.0f / (float)max(end - beg, 1);
    float2 o;
    o.x = (a0x + a1x + a2x + a3x) * inv;
    o.y = (a0y + a1y + a2y + a3y) * inv;
    *(float2*)(agg + (size_t)node * 128 + lane * 2) = o;
  }
}

// ---------------- fused SAGE linear: h = relu([agg, xin] @ [Wl;Wr] + b) ----------------
// weight (256x128 f32 = 128KB) in LDS; 1024 threads (16 waves/CU); wave does 8 rows,
// row data read as wave-uniform (scalar) loads straight from global.

__global__ __launch_bounds__(1024)
void k_linear(const float* __restrict__ agg, const float* __restrict__ xin,
              const float* __restrict__ Wl, const float* __restrict__ Wr,
              const float* __restrict__ bias, float* __restrict__ hout, int M) {
  __shared__ float Wlds[256 * 128];
  const int tid = threadIdx.x;
  for (int i = tid; i < 8192; i += 1024) {
    int f = i * 4;
    float4 v = (f < 16384) ? *(const float4*)(Wl + f)
                           : *(const float4*)(Wr + (f - 16384));
    *(float4*)(&Wlds[f]) = v;
  }
  __syncthreads();
  const int lane = tid & 63;
  const int w = __builtin_amdgcn_readfirstlane(tid >> 6);
  const float bl0 = bias[2 * lane], bl1 = bias[2 * lane + 1];
  const int stride = gridDim.x * 128;
  for (int base = blockIdx.x * 128 + w * 8; base < M; base += stride) {
    float acc[8][2];
    #pragma unroll
    for (int r = 0; r < 8; ++r) { acc[r][0] = 0.f; acc[r][1] = 0.f; }
    #pragma unroll
    for (int seg = 0; seg < 2; ++seg) {
      const float* sb = seg ? xin : agg;
      const int wofs = seg ? 128 : 0;
      const float* p[8];
      #pragma unroll
      for (int r = 0; r < 8; ++r) {
        int rg = min(base + r, M - 1);
        p[r] = sb + (size_t)rg * 128;
      }
      for (int k = 0; k < 128; k += 4) {
        float4 a[8];
        #pragma unroll
        for (int r = 0; r < 8; ++r) a[r] = *(const float4*)(p[r] + k);
        #pragma unroll
        for (int kk = 0; kk < 4; ++kk) {
          float2 wv = *(const float2*)(&Wlds[(wofs + k + kk) * 128 + (lane << 1)]);
          #pragma unroll
          for (int r = 0; r < 8; ++r) {
            float e = ((const float*)&a[r])[kk];
            acc[r][0] += e * wv.x;
            acc[r][1] += e * wv.y;
          }
        }
      }
    }
    #pragma unroll
    for (int r = 0; r < 8; ++r) {
      int rg = base + r;
      if (rg < M) {
        float2 o;
        o.x = fmaxf(acc[r][0] + bl0, 0.f);
        o.y = fmaxf(acc[r][1] + bl1, 0.f);
        *(float2*)(&hout[(size_t)rg * 128 + (lane << 1)]) = o;
      }
    }
  }
}

// ---------------- classifier: out = relu([h2[bs],h2[bd],feat] @ Wc1 + bc1) @ Wc2 + bc2 ----------------
// Wc1 (288x128 f32 = 144KB) in LDS; 1024 threads; wave does 8 edges; row data via
// wave-uniform gathers from global (no LDS row staging).

__global__ __launch_bounds__(1024)
void k_cls(const float* __restrict__ h2, const int* __restrict__ bs,
           const int* __restrict__ bd, const float* __restrict__ feat,
           const float* __restrict__ Wc1, const float* __restrict__ bc1,
           const float* __restrict__ Wc2, const float* __restrict__ bc2,
           float* __restrict__ out, int M) {
  __shared__ float Wlds[288 * 128];
  const int tid = threadIdx.x;
  for (int i = tid; i < 9216; i += 1024) {
    *(float4*)(&Wlds[i * 4]) = *(const float4*)(Wc1 + i * 4);
  }
  __syncthreads();
  const int lane = tid & 63;
  const int w = __builtin_amdgcn_readfirstlane(tid >> 6);
  const float bl0 = bc1[2 * lane], bl1 = bc1[2 * lane + 1];
  const float wv0 = Wc2[2 * lane], wv1 = Wc2[2 * lane + 1];
  const float bc2v = bc2[0];
  const int stride = gridDim.x * 128;
  for (int base = blockIdx.x * 128 + w * 8; base < M; base += stride) {
    float acc[8][2];
    #pragma unroll
    for (int r = 0; r < 8; ++r) { acc[r][0] = 0.f; acc[r][1] = 0.f; }

    // segments A (h2[bs], W rows 0..127) and B (h2[bd], W rows 128..255)
    #pragma unroll
    for (int seg = 0; seg < 2; ++seg) {
      const int* idx = seg ? bd : bs;
      const int wofs = seg ? 128 : 0;
      const float* p[8];
      #pragma unroll
      for (int r = 0; r < 8; ++r) {
        int rg = min(base + r, M - 1);
        p[r] = h2 + (size_t)__builtin_amdgcn_readfirstlane(idx[rg]) * 128;
      }
      for (int k = 0; k < 128; k += 4) {
        float4 a[8];
        #pragma unroll
        for (int r = 0; r < 8; ++r) a[r] = *(const float4*)(p[r] + k);
        #pragma unroll
        for (int kk = 0; kk < 4; ++kk) {
          float2 wv = *(const float2*)(&Wlds[(wofs + k + kk) * 128 + (lane << 1)]);
          #pragma unroll
          for (int r = 0; r < 8; ++r) {
            float e = ((const float*)&a[r])[kk];
            acc[r][0] += e * wv.x;
            acc[r][1] += e * wv.y;
          }
        }
      }
    }
    // segment C: feat (W rows 256..287)
    {
      const float* p[8];
      #pragma unroll
      for (int r = 0; r < 8; ++r) {
        int rg = min(base + r, M - 1);
        p[r] = feat + (size_t)rg * 32;
      }
      for (int k = 0; k < 32; k += 4) {
        float4 a[8];
        #pragma unroll
        for (int r = 0; r < 8; ++r) a[r] = *(const float4*)(p[r] + k);
        #pragma unroll
        for (int kk = 0; kk < 4; ++kk) {
          float2 wv = *(const float2*)(&Wlds[(256 + k + kk) * 128 + (lane << 1)]);
          #pragma unroll
          for (int r = 0; r < 8; ++r) {
            float e = ((const float*)&a[r])[kk];
            acc[r][0] += e * wv.x;
            acc[r][1] += e * wv.y;
          }
        }
      }
    }
    // epilogue: relu, second linear (dot with Wc2), wave reduce, store
    #pragma unroll
    for (int r = 0; r < 8; ++r) {
      float z0 = fmaxf(acc[r][0] + bl0, 0.f);
      float z1 = fmaxf(acc[r][1] + bl1, 0.f);
      float pr = z0 * wv0 + z1 * wv1;
      #pragma unroll
      for (int d = 32; d >= 1; d >>= 1) pr += __shfl_xor(pr, d);
      int rg = base + r;
      if (lane == 0 && rg < M) out[rg] = pr + bc2v;
    }
  }
}

// ---------------- launcher ----------------

extern "C" void kernel_launch(void* const* d_in, const int* in_sizes, int n_in,
                              void* d_out, int out_size, void* d_ws, size_t ws_size,
                              hipStream_t stream) {
  const float* x    = (const float*)d_in[0];
  const int*   ei   = (const int*)d_in[1];
  const int*   bei  = (const int*)d_in[2];
  const float* feat = (const float*)d_in[3];
  const float* W1l  = (const float*)d_in[4];
  const float* b1   = (const float*)d_in[5];
  const float* W1r  = (const float*)d_in[6];
  const float* W2l  = (const float*)d_in[7];
  const float* b2   = (const float*)d_in[8];
  const float* W2r  = (const float*)d_in[9];
  const float* Wc1  = (const float*)d_in[10];
  const float* bc1  = (const float*)d_in[11];
  const float* Wc2  = (const float*)d_in[12];
  const float* bc2  = (const float*)d_in[13];
  float* out = (float*)d_out;

  const int E  = in_sizes[1] / 2;   // 800000
  const int EB = in_sizes[2] / 2;   // 200000
  const int* src = ei;
  const int* dst = ei + E;
  const int* bs = bei;
  const int* bd = bei + EB;

  char* ws = (char*)d_ws;
  int*   cnt    = (int*)(ws + 0);
  int*   offs   = (int*)(ws + (256u << 10));
  int*   cursor = (int*)(ws + (512u << 10));
  int*   nbr    = (int*)(ws + (768u << 10));              // E ints = 3.2MB
  float* agg    = (float*)(ws + (8ull << 20));            // 25.6MB
  float* h1     = (float*)(ws + (40ull << 20));           // 25.6MB
  float* h2     = (float*)(ws + (72ull << 20));           // 25.6MB

  hipMemsetAsync(cnt, 0, N_NODES * sizeof(int), stream);

  const int eb = (E + 255) / 256;
  k_hist<<<eb, 256, 0, stream>>>(dst, cnt, E);
  k_scan<<<1, 1024, 0, stream>>>(cnt, offs, cursor, N_NODES);
  k_fill<<<eb, 256, 0, stream>>>(src, dst, cursor, nbr, E);

  // layer 1
  k_agg<<<2048, 256, 0, stream>>>(x, offs, nbr, agg, N_NODES);
  k_linear<<<256, 1024, 0, stream>>>(agg, x, W1l, W1r, b1, h1, N_NODES);
  // layer 2
  k_agg<<<2048, 256, 0, stream>>>(h1, offs, nbr, agg, N_NODES);
  k_linear<<<256, 1024, 0, stream>>>(agg, h1, W2l, W2r, b2, h2, N_NODES);
  // classifier
  k_cls<<<256, 1024, 0, stream>>>(h2, bs, bd, feat, Wc1, bc1, Wc2, bc2, out, EB);
}

// Round 3
// 599.720 us; speedup vs baseline: 1.9199x; 1.5070x over previous
//
#include <hip/hip_runtime.h>

#define N_NODES 50000

typedef unsigned short ushort_t;
typedef unsigned int uint_t;
typedef ushort_t ushort8 __attribute__((ext_vector_type(8)));
typedef __bf16 bf16x8 __attribute__((ext_vector_type(8)));
typedef float f32x4 __attribute__((ext_vector_type(4)));

__device__ inline ushort_t f2bf(float f) {
  union { float f; uint_t u; } v; v.f = f;
  uint_t u = v.u;
  uint_t r = (u + 0x7fffu + ((u >> 16) & 1u)) >> 16;  // round-to-nearest-even
  return (ushort_t)r;
}

// ---------------- CSR build ----------------

__global__ void k_hist(const int* __restrict__ dst, int* __restrict__ cnt, int E) {
  int t = blockIdx.x * blockDim.x + threadIdx.x;
  if (t < E) atomicAdd(&cnt[dst[t]], 1);
}

__global__ void k_scan(const int* __restrict__ cnt, int* __restrict__ offs,
                       int* __restrict__ cursor, int n) {
  __shared__ int part[1024];
  const int tid = threadIdx.x;
  const int C = (n + 1023) >> 10;
  const int beg = tid * C;
  const int end = min(beg + C, n);
  int s = 0;
  for (int i = beg; i < end; ++i) s += cnt[i];
  part[tid] = s;
  __syncthreads();
  for (int d = 1; d < 1024; d <<= 1) {
    int v = (tid >= d) ? part[tid - d] : 0;
    __syncthreads();
    part[tid] += v;
    __syncthreads();
  }
  int run = (tid == 0) ? 0 : part[tid - 1];
  for (int i = beg; i < end; ++i) {
    offs[i] = run; cursor[i] = run; run += cnt[i];
  }
  if (tid == (n - 1) / C) offs[n] = run;
}

__global__ void k_fill(const int* __restrict__ src, const int* __restrict__ dst,
                       int* __restrict__ cursor, int* __restrict__ nbr, int E) {
  int t = blockIdx.x * blockDim.x + threadIdx.x;
  if (t < E) {
    int p = atomicAdd(&cursor[dst[t]], 1);
    nbr[p] = src[t];
  }
}

// ---------------- prep: feat -> bf16, Wc1 -> bf16 transposed [col][k] ----------------

__global__ void k_prep(const float* __restrict__ feat, ushort_t* __restrict__ featb, int nfeat,
                       const float* __restrict__ Wc1, ushort_t* __restrict__ wt) {
  int t = blockIdx.x * blockDim.x + threadIdx.x;
  if (t < nfeat) featb[t] = f2bf(feat[t]);
  if (t < 128 * 288) {
    int c = t / 288, k = t % 288;
    wt[t] = f2bf(Wc1[k * 128 + c]);
  }
}

// ---------------- mean aggregation (gather) ----------------

__global__ void k_agg(const float* __restrict__ x, const int* __restrict__ offs,
                      const int* __restrict__ nbr, float* __restrict__ agg, int n) {
  const int lane = threadIdx.x & 63;
  const int w = (int)((blockIdx.x * blockDim.x + threadIdx.x) >> 6);
  const int nw = (int)((gridDim.x * blockDim.x) >> 6);
  for (int node = w; node < n; node += nw) {
    const int beg = offs[node], end = offs[node + 1];
    float a0x = 0.f, a0y = 0.f, a1x = 0.f, a1y = 0.f;
    float a2x = 0.f, a2y = 0.f, a3x = 0.f, a3y = 0.f;
    int j = beg;
    for (; j + 4 <= end; j += 4) {
      int s0 = __builtin_amdgcn_readfirstlane(nbr[j]);
      int s1 = __builtin_amdgcn_readfirstlane(nbr[j + 1]);
      int s2 = __builtin_amdgcn_readfirstlane(nbr[j + 2]);
      int s3 = __builtin_amdgcn_readfirstlane(nbr[j + 3]);
      float2 v0 = *(const float2*)(x + (size_t)s0 * 128 + lane * 2);
      float2 v1 = *(const float2*)(x + (size_t)s1 * 128 + lane * 2);
      float2 v2 = *(const float2*)(x + (size_t)s2 * 128 + lane * 2);
      float2 v3 = *(const float2*)(x + (size_t)s3 * 128 + lane * 2);
      a0x += v0.x; a0y += v0.y; a1x += v1.x; a1y += v1.y;
      a2x += v2.x; a2y += v2.y; a3x += v3.x; a3y += v3.y;
    }
    for (; j < end; ++j) {
      int s0 = __builtin_amdgcn_readfirstlane(nbr[j]);
      float2 v0 = *(const float2*)(x + (size_t)s0 * 128 + lane * 2);
      a0x += v0.x; a0y += v0.y;
    }
    float inv = 1.0f / (float)max(end - beg, 1);
    float2 o;
    o.x = (a0x + a1x + a2x + a3x) * inv;
    o.y = (a0y + a1y + a2y + a3y) * inv;
    *(float2*)(agg + (size_t)node * 128 + lane * 2) = o;
  }
}

// ---------------- fused SAGE linear: h = relu([agg, xin] @ [Wl;Wr] + b) ----------------

template<bool BF16OUT>
__global__ __launch_bounds__(1024)
void k_linear(const float* __restrict__ agg, const float* __restrict__ xin,
              const float* __restrict__ Wl, const float* __restrict__ Wr,
              const float* __restrict__ bias, float* __restrict__ hout,
              ushort_t* __restrict__ houtb, int M) {
  __shared__ float Wlds[256 * 128];
  const int tid = threadIdx.x;
  for (int i = tid; i < 8192; i += 1024) {
    int f = i * 4;
    float4 v = (f < 16384) ? *(const float4*)(Wl + f)
                           : *(const float4*)(Wr + (f - 16384));
    *(float4*)(&Wlds[f]) = v;
  }
  __syncthreads();
  const int lane = tid & 63;
  const int w = __builtin_amdgcn_readfirstlane(tid >> 6);
  const float bl0 = bias[2 * lane], bl1 = bias[2 * lane + 1];
  const int stride = gridDim.x * 128;
  for (int base = blockIdx.x * 128 + w * 8; base < M; base += stride) {
    float acc[8][2];
    #pragma unroll
    for (int r = 0; r < 8; ++r) { acc[r][0] = 0.f; acc[r][1] = 0.f; }
    #pragma unroll
    for (int seg = 0; seg < 2; ++seg) {
      const float* sb = seg ? xin : agg;
      const int wofs = seg ? 128 : 0;
      const float* p[8];
      #pragma unroll
      for (int r = 0; r < 8; ++r) {
        int rg = min(base + r, M - 1);
        p[r] = sb + (size_t)rg * 128;
      }
      for (int k = 0; k < 128; k += 4) {
        float4 a[8];
        #pragma unroll
        for (int r = 0; r < 8; ++r) a[r] = *(const float4*)(p[r] + k);
        #pragma unroll
        for (int kk = 0; kk < 4; ++kk) {
          float2 wv = *(const float2*)(&Wlds[(wofs + k + kk) * 128 + (lane << 1)]);
          #pragma unroll
          for (int r = 0; r < 8; ++r) {
            float e = ((const float*)&a[r])[kk];
            acc[r][0] += e * wv.x;
            acc[r][1] += e * wv.y;
          }
        }
      }
    }
    #pragma unroll
    for (int r = 0; r < 8; ++r) {
      int rg = base + r;
      if (rg < M) {
        float o0 = fmaxf(acc[r][0] + bl0, 0.f);
        float o1 = fmaxf(acc[r][1] + bl1, 0.f);
        if (BF16OUT) {
          uint_t pk = (uint_t)f2bf(o0) | ((uint_t)f2bf(o1) << 16);
          *(uint_t*)(&houtb[(size_t)rg * 128 + (lane << 1)]) = pk;
        } else {
          float2 o; o.x = o0; o.y = o1;
          *(float2*)(&hout[(size_t)rg * 128 + (lane << 1)]) = o;
        }
      }
    }
  }
}

// ---------------- classifier via bf16 MFMA ----------------
// C[e][col] = sum_k A[e][k] * Wc1[k][col], A = [h2[bs], h2[bd], feat] (bf16), acc fp32.
// Block: 256 thr = 4 waves; wave w owns cols w*32..w*32+31 (2 col-tiles of 16).
// B-frags (Wc1) held in registers for whole kernel; 64 edges staged in LDS per iter.

__global__ __launch_bounds__(256)
void k_cls_mfma(const ushort_t* __restrict__ h2b, const int* __restrict__ bs,
                const int* __restrict__ bd, const ushort_t* __restrict__ featb,
                const ushort_t* __restrict__ wt, const float* __restrict__ bc1,
                const float* __restrict__ Wc2, const float* __restrict__ bc2,
                float* __restrict__ out, int M) {
  __shared__ ushort_t rows[64][296];   // [edge][k], k: 0-127 bs-row, 128-255 bd-row, 256-287 feat
  __shared__ float outs[64];
  const int tid = threadIdx.x;
  const int lane = tid & 63;
  const int w = tid >> 6;
  const int l4 = lane & 15, lg = lane >> 4;

  // B fragments: lane l needs Wc1[k = kt*32 + lg*8 + j][col = c0 + l4], wt is [col][k]
  bf16x8 bfrag[9][2];
  #pragma unroll
  for (int kt = 0; kt < 9; ++kt)
    #pragma unroll
    for (int ct = 0; ct < 2; ++ct) {
      int col = w * 32 + ct * 16 + l4;
      bfrag[kt][ct] = __builtin_bit_cast(bf16x8,
          *(const ushort8*)(wt + (size_t)col * 288 + kt * 32 + lg * 8));
    }
  const int col0 = w * 32 + l4, col1 = col0 + 16;
  const float b0 = bc1[col0], b1 = bc1[col1];
  const float w20 = Wc2[col0], w21 = Wc2[col1];
  const float bc2v = bc2[0];

  const int niter = (M + 63) >> 6;
  for (int it = blockIdx.x; it < niter; it += gridDim.x) {
    const int m0 = it << 6;
    __syncthreads();
    // stage 64 edges x 576B of bf16 row data (2304 16B chunks, 9 per thread)
    #pragma unroll
    for (int c = 0; c < 9; ++c) {
      int q = c * 256 + tid;
      if (q < 1024) {
        int e = q >> 4, ch = q & 15;
        int idx = bs[min(m0 + e, M - 1)];
        *(ushort8*)(&rows[e][ch * 8]) = *(const ushort8*)(h2b + (size_t)idx * 128 + ch * 8);
      } else if (q < 2048) {
        int q2 = q - 1024; int e = q2 >> 4, ch = q2 & 15;
        int idx = bd[min(m0 + e, M - 1)];
        *(ushort8*)(&rows[e][128 + ch * 8]) = *(const ushort8*)(h2b + (size_t)idx * 128 + ch * 8);
      } else {
        int q2 = q - 2048; int e = q2 >> 2, ch = q2 & 3;
        int eg = min(m0 + e, M - 1);
        *(ushort8*)(&rows[e][256 + ch * 8]) = *(const ushort8*)(featb + (size_t)eg * 32 + ch * 8);
      }
    }
    if (tid < 64) outs[tid] = 0.f;
    __syncthreads();

    f32x4 acc[4][2];
    #pragma unroll
    for (int ms = 0; ms < 4; ++ms) {
      acc[ms][0] = (f32x4)0.f; acc[ms][1] = (f32x4)0.f;
    }
    #pragma unroll
    for (int kt = 0; kt < 9; ++kt) {
      bf16x8 af[4];
      #pragma unroll
      for (int ms = 0; ms < 4; ++ms)
        af[ms] = __builtin_bit_cast(bf16x8,
            *(const ushort8*)(&rows[ms * 16 + l4][kt * 32 + lg * 8]));
      #pragma unroll
      for (int ms = 0; ms < 4; ++ms) {
        acc[ms][0] = __builtin_amdgcn_mfma_f32_16x16x32_bf16(af[ms], bfrag[kt][0], acc[ms][0], 0, 0, 0);
        acc[ms][1] = __builtin_amdgcn_mfma_f32_16x16x32_bf16(af[ms], bfrag[kt][1], acc[ms][1], 0, 0, 0);
      }
    }
    // epilogue: D row (edge-in-tile) = lg*4 + r, col = l4 (+16*ct +32*w); all fp32
    #pragma unroll
    for (int ms = 0; ms < 4; ++ms) {
      #pragma unroll
      for (int r = 0; r < 4; ++r) {
        float z0 = fmaxf(acc[ms][0][r] + b0, 0.f);
        float z1 = fmaxf(acc[ms][1][r] + b1, 0.f);
        float v = z0 * w20 + z1 * w21;
        v += __shfl_xor(v, 1); v += __shfl_xor(v, 2);
        v += __shfl_xor(v, 4); v += __shfl_xor(v, 8);
        if (l4 == 0) atomicAdd(&outs[ms * 16 + lg * 4 + r], v);
      }
    }
    __syncthreads();
    if (tid < 64 && m0 + tid < M) out[m0 + tid] = outs[tid] + bc2v;
  }
}

// ---------------- launcher ----------------

extern "C" void kernel_launch(void* const* d_in, const int* in_sizes, int n_in,
                              void* d_out, int out_size, void* d_ws, size_t ws_size,
                              hipStream_t stream) {
  const float* x    = (const float*)d_in[0];
  const int*   ei   = (const int*)d_in[1];
  const int*   bei  = (const int*)d_in[2];
  const float* feat = (const float*)d_in[3];
  const float* W1l  = (const float*)d_in[4];
  const float* b1   = (const float*)d_in[5];
  const float* W1r  = (const float*)d_in[6];
  const float* W2l  = (const float*)d_in[7];
  const float* b2   = (const float*)d_in[8];
  const float* W2r  = (const float*)d_in[9];
  const float* Wc1  = (const float*)d_in[10];
  const float* bc1  = (const float*)d_in[11];
  const float* Wc2  = (const float*)d_in[12];
  const float* bc2  = (const float*)d_in[13];
  float* out = (float*)d_out;

  const int E  = in_sizes[1] / 2;   // 800000
  const int EB = in_sizes[2] / 2;   // 200000
  const int* src = ei;
  const int* dst = ei + E;
  const int* bs = bei;
  const int* bd = bei + EB;

  char* ws = (char*)d_ws;
  int*      cnt    = (int*)(ws + 0);
  int*      offs   = (int*)(ws + (256u << 10));
  int*      cursor = (int*)(ws + (512u << 10));
  int*      nbr    = (int*)(ws + (768u << 10));            // E ints = 3.2MB
  float*    agg    = (float*)(ws + (8ull << 20));          // 25.6MB
  float*    h1     = (float*)(ws + (40ull << 20));         // 25.6MB
  ushort_t* h2b    = (ushort_t*)(ws + (72ull << 20));      // 12.8MB bf16
  ushort_t* featb  = (ushort_t*)(ws + (88ull << 20));      // 12.8MB bf16
  ushort_t* wt     = (ushort_t*)(ws + (104ull << 20));     // 72KB bf16 [128][288]

  hipMemsetAsync(cnt, 0, N_NODES * sizeof(int), stream);

  const int eb = (E + 255) / 256;
  k_hist<<<eb, 256, 0, stream>>>(dst, cnt, E);
  k_scan<<<1, 1024, 0, stream>>>(cnt, offs, cursor, N_NODES);
  k_fill<<<eb, 256, 0, stream>>>(src, dst, cursor, nbr, E);

  // prep bf16 inputs for classifier
  const int nfeat = EB * 32;
  k_prep<<<(nfeat + 255) / 256, 256, 0, stream>>>(feat, featb, nfeat, Wc1, wt);

  // layer 1 (fp32)
  k_agg<<<2048, 256, 0, stream>>>(x, offs, nbr, agg, N_NODES);
  k_linear<false><<<256, 1024, 0, stream>>>(agg, x, W1l, W1r, b1, h1, nullptr, N_NODES);
  // layer 2 (fp32 compute, bf16 output for classifier)
  k_agg<<<2048, 256, 0, stream>>>(h1, offs, nbr, agg, N_NODES);
  k_linear<true><<<256, 1024, 0, stream>>>(agg, h1, W2l, W2r, b2, nullptr, h2b, N_NODES);
  // classifier (bf16 MFMA)
  k_cls_mfma<<<768, 256, 0, stream>>>(h2b, bs, bd, featb, wt, bc1, Wc2, bc2, out, EB);
}

// Round 4
// 274.079 us; speedup vs baseline: 4.2010x; 2.1881x over previous
//
#include <hip/hip_runtime.h>

#define N_NODES 50000

typedef unsigned short ushort_t;
typedef unsigned int uint_t;
typedef ushort_t ushort8 __attribute__((ext_vector_type(8)));
typedef __bf16 bf16x8 __attribute__((ext_vector_type(8)));
typedef float f32x4 __attribute__((ext_vector_type(4)));

__device__ inline ushort_t f2bf(float f) {
  union { float f; uint_t u; } v; v.f = f;
  uint_t u = v.u;
  uint_t r = (u + 0x7fffu + ((u >> 16) & 1u)) >> 16;  // RNE
  return (ushort_t)r;
}
__device__ inline uint_t pack2bf(float a, float b) {
  return (uint_t)f2bf(a) | ((uint_t)f2bf(b) << 16);
}
__device__ inline float bflo(uint_t u) { union { uint_t u; float f; } v; v.u = u << 16; return v.f; }
__device__ inline float bfhi(uint_t u) { union { uint_t u; float f; } v; v.u = u & 0xffff0000u; return v.f; }

// ---------------- CSR build ----------------

__global__ void k_hist(const int* __restrict__ dst, int* __restrict__ cnt, int E) {
  int t = blockIdx.x * blockDim.x + threadIdx.x;
  if (t < E) atomicAdd(&cnt[dst[t]], 1);
}

// decoupled scan: 1) per-block sums  2) scan of block sums  3) local scan + add
__global__ void k_scan1(const int* __restrict__ cnt, int* __restrict__ bsum, int n) {
  __shared__ int s[256];
  int t = blockIdx.x * 256 + threadIdx.x;
  int v = (t < n) ? cnt[t] : 0;
  s[threadIdx.x] = v;
  __syncthreads();
  for (int d = 128; d; d >>= 1) {
    if (threadIdx.x < d) s[threadIdx.x] += s[threadIdx.x + d];
    __syncthreads();
  }
  if (threadIdx.x == 0) bsum[blockIdx.x] = s[0];
}

__global__ void k_scan2(const int* __restrict__ bsum, int* __restrict__ bpre,
                        int nb, int* __restrict__ offs, int n) {
  __shared__ int s[256];
  int tid = threadIdx.x;
  int v = (tid < nb) ? bsum[tid] : 0;
  s[tid] = v;
  __syncthreads();
  for (int d = 1; d < 256; d <<= 1) {
    int u = (tid >= d) ? s[tid - d] : 0;
    __syncthreads();
    s[tid] += u;
    __syncthreads();
  }
  if (tid < nb) bpre[tid] = s[tid] - v;
  if (tid == nb - 1) offs[n] = s[tid];
}

__global__ void k_scan3(const int* __restrict__ cnt, const int* __restrict__ bpre,
                        int* __restrict__ offs, int* __restrict__ cursor, int n) {
  __shared__ int s[256];
  int tid = threadIdx.x;
  int t = blockIdx.x * 256 + tid;
  int v = (t < n) ? cnt[t] : 0;
  s[tid] = v;
  __syncthreads();
  for (int d = 1; d < 256; d <<= 1) {
    int u = (tid >= d) ? s[tid - d] : 0;
    __syncthreads();
    s[tid] += u;
    __syncthreads();
  }
  if (t < n) {
    int ex = bpre[blockIdx.x] + s[tid] - v;
    offs[t] = ex; cursor[t] = ex;
  }
}

__global__ void k_fill(const int* __restrict__ src, const int* __restrict__ dst,
                       int* __restrict__ cursor, int* __restrict__ nbr, int E) {
  int t = blockIdx.x * blockDim.x + threadIdx.x;
  if (t < E) {
    int p = atomicAdd(&cursor[dst[t]], 1);
    nbr[p] = src[t];
  }
}

// ---------------- prep: x,feat -> bf16; weights -> bf16 transposed [col][k] ----------------

__global__ void k_prep(const float* __restrict__ x, ushort_t* __restrict__ xb,
                       const float* __restrict__ feat, ushort_t* __restrict__ featb,
                       const float* __restrict__ W1l, const float* __restrict__ W1r,
                       ushort_t* __restrict__ wt1,
                       const float* __restrict__ W2l, const float* __restrict__ W2r,
                       ushort_t* __restrict__ wt2,
                       const float* __restrict__ Wc1, ushort_t* __restrict__ wtc) {
  int bid = blockIdx.x, tid = threadIdx.x;
  if (bid < 6250) {                      // x: 6.4M elems as 1.6M float4
    int t = bid * 256 + tid;
    float4 v = *(const float4*)(x + (size_t)t * 4);
    uint2 p; p.x = pack2bf(v.x, v.y); p.y = pack2bf(v.z, v.w);
    *(uint2*)(xb + (size_t)t * 4) = p;
  } else if (bid < 12500) {              // feat: 6.4M elems
    int t = (bid - 6250) * 256 + tid;
    float4 v = *(const float4*)(feat + (size_t)t * 4);
    uint2 p; p.x = pack2bf(v.x, v.y); p.y = pack2bf(v.z, v.w);
    *(uint2*)(featb + (size_t)t * 4) = p;
  } else {                               // weight transposes
    int t = (bid - 12500) * 256 + tid;
    if (t < 32768) {
      int c = t >> 8, k = t & 255;
      wt1[t] = f2bf(k < 128 ? W1l[k * 128 + c] : W1r[(k - 128) * 128 + c]);
    } else if (t < 65536) {
      int t2 = t - 32768; int c = t2 >> 8, k = t2 & 255;
      wt2[t2] = f2bf(k < 128 ? W2l[k * 128 + c] : W2r[(k - 128) * 128 + c]);
    } else if (t < 65536 + 36864) {
      int t3 = t - 65536; int c = t3 / 288, k = t3 % 288;
      wtc[t3] = f2bf(Wc1[k * 128 + c]);
    }
  }
}

// ---------------- mean aggregation (bf16 gather, fp32 accum, bf16 out) ----------------

__global__ void k_agg(const ushort_t* __restrict__ xb, const int* __restrict__ offs,
                      const int* __restrict__ nbr, ushort_t* __restrict__ aggb, int n) {
  const int lane = threadIdx.x & 63;
  const int w = (int)((blockIdx.x * blockDim.x + threadIdx.x) >> 6);
  const int nw = (int)((gridDim.x * blockDim.x) >> 6);
  for (int node = w; node < n; node += nw) {
    const int beg = offs[node], end = offs[node + 1];
    float ax0 = 0.f, ay0 = 0.f, ax1 = 0.f, ay1 = 0.f;
    float ax2 = 0.f, ay2 = 0.f, ax3 = 0.f, ay3 = 0.f;
    int j = beg;
    for (; j + 8 <= end; j += 8) {
      uint_t u[8];
      #pragma unroll
      for (int r = 0; r < 8; ++r) {
        int s = __builtin_amdgcn_readfirstlane(nbr[j + r]);
        u[r] = *(const uint_t*)(xb + (size_t)s * 128 + lane * 2);
      }
      ax0 += bflo(u[0]); ay0 += bfhi(u[0]); ax1 += bflo(u[1]); ay1 += bfhi(u[1]);
      ax2 += bflo(u[2]); ay2 += bfhi(u[2]); ax3 += bflo(u[3]); ay3 += bfhi(u[3]);
      ax0 += bflo(u[4]); ay0 += bfhi(u[4]); ax1 += bflo(u[5]); ay1 += bfhi(u[5]);
      ax2 += bflo(u[6]); ay2 += bfhi(u[6]); ax3 += bflo(u[7]); ay3 += bfhi(u[7]);
    }
    for (; j < end; ++j) {
      int s = __builtin_amdgcn_readfirstlane(nbr[j]);
      uint_t u0 = *(const uint_t*)(xb + (size_t)s * 128 + lane * 2);
      ax0 += bflo(u0); ay0 += bfhi(u0);
    }
    float inv = 1.0f / (float)max(end - beg, 1);
    float ox = (ax0 + ax1 + ax2 + ax3) * inv;
    float oy = (ay0 + ay1 + ay2 + ay3) * inv;
    *(uint_t*)(aggb + (size_t)node * 128 + lane * 2) = pack2bf(ox, oy);
  }
}

// ---------------- SAGE linear via bf16 MFMA: h = relu([agg, xin] @ Wt^T + b) ----------------
// A rows staged in LDS (stride 258 bf16 = 129 words -> conflict-free), B frags in regs.

__global__ __launch_bounds__(256)
void k_linear_mfma(const ushort_t* __restrict__ aggb, const ushort_t* __restrict__ xinb,
                   const ushort_t* __restrict__ wt, const float* __restrict__ bias,
                   ushort_t* __restrict__ houtb, int M) {
  __shared__ ushort_t rows[64][258];
  const int tid = threadIdx.x;
  const int lane = tid & 63;
  const int w = tid >> 6;
  const int l4 = lane & 15, lg = lane >> 4;

  bf16x8 bfrag[8][2];
  #pragma unroll
  for (int kt = 0; kt < 8; ++kt)
    #pragma unroll
    for (int ct = 0; ct < 2; ++ct) {
      int col = w * 32 + ct * 16 + l4;
      bfrag[kt][ct] = __builtin_bit_cast(bf16x8,
          *(const ushort8*)(wt + (size_t)col * 256 + kt * 32 + lg * 8));
    }
  const int col0 = w * 32 + l4, col1 = col0 + 16;
  const float b0 = bias[col0], b1 = bias[col1];

  const int niter = (M + 63) >> 6;
  for (int it = blockIdx.x; it < niter; it += gridDim.x) {
    const int m0 = it << 6;
    __syncthreads();
    #pragma unroll
    for (int c = 0; c < 8; ++c) {
      int q = c * 256 + tid;
      int e = q >> 5, ch = q & 31;
      int rg = min(m0 + e, M - 1);
      const ushort_t* p = (ch < 16) ? (aggb + (size_t)rg * 128 + ch * 8)
                                    : (xinb + (size_t)rg * 128 + (ch - 16) * 8);
      *(ushort8*)(&rows[e][ch * 8]) = *(const ushort8*)p;
    }
    __syncthreads();

    f32x4 acc[4][2];
    #pragma unroll
    for (int ms = 0; ms < 4; ++ms) { acc[ms][0] = (f32x4)0.f; acc[ms][1] = (f32x4)0.f; }
    #pragma unroll
    for (int kt = 0; kt < 8; ++kt) {
      bf16x8 af[4];
      #pragma unroll
      for (int ms = 0; ms < 4; ++ms)
        af[ms] = __builtin_bit_cast(bf16x8,
            *(const ushort8*)(&rows[ms * 16 + l4][kt * 32 + lg * 8]));
      #pragma unroll
      for (int ms = 0; ms < 4; ++ms) {
        acc[ms][0] = __builtin_amdgcn_mfma_f32_16x16x32_bf16(af[ms], bfrag[kt][0], acc[ms][0], 0, 0, 0);
        acc[ms][1] = __builtin_amdgcn_mfma_f32_16x16x32_bf16(af[ms], bfrag[kt][1], acc[ms][1], 0, 0, 0);
      }
    }
    #pragma unroll
    for (int ms = 0; ms < 4; ++ms)
      #pragma unroll
      for (int r = 0; r < 4; ++r) {
        int rg = m0 + ms * 16 + lg * 4 + r;
        if (rg < M) {
          houtb[(size_t)rg * 128 + col0] = f2bf(fmaxf(acc[ms][0][r] + b0, 0.f));
          houtb[(size_t)rg * 128 + col1] = f2bf(fmaxf(acc[ms][1][r] + b1, 0.f));
        }
      }
  }
}

// ---------------- classifier via bf16 MFMA ----------------

__global__ __launch_bounds__(256)
void k_cls_mfma(const ushort_t* __restrict__ h2b, const int* __restrict__ bs,
                const int* __restrict__ bd, const ushort_t* __restrict__ featb,
                const ushort_t* __restrict__ wt, const float* __restrict__ bc1,
                const float* __restrict__ Wc2, const float* __restrict__ bc2,
                float* __restrict__ out, int M) {
  __shared__ ushort_t rows[64][296];
  __shared__ float outs[64];
  const int tid = threadIdx.x;
  const int lane = tid & 63;
  const int w = tid >> 6;
  const int l4 = lane & 15, lg = lane >> 4;

  bf16x8 bfrag[9][2];
  #pragma unroll
  for (int kt = 0; kt < 9; ++kt)
    #pragma unroll
    for (int ct = 0; ct < 2; ++ct) {
      int col = w * 32 + ct * 16 + l4;
      bfrag[kt][ct] = __builtin_bit_cast(bf16x8,
          *(const ushort8*)(wt + (size_t)col * 288 + kt * 32 + lg * 8));
    }
  const int col0 = w * 32 + l4, col1 = col0 + 16;
  const float b0 = bc1[col0], b1 = bc1[col1];
  const float w20 = Wc2[col0], w21 = Wc2[col1];
  const float bc2v = bc2[0];

  const int niter = (M + 63) >> 6;
  for (int it = blockIdx.x; it < niter; it += gridDim.x) {
    const int m0 = it << 6;
    __syncthreads();
    #pragma unroll
    for (int c = 0; c < 9; ++c) {
      int q = c * 256 + tid;
      if (q < 1024) {
        int e = q >> 4, ch = q & 15;
        int idx = bs[min(m0 + e, M - 1)];
        *(ushort8*)(&rows[e][ch * 8]) = *(const ushort8*)(h2b + (size_t)idx * 128 + ch * 8);
      } else if (q < 2048) {
        int q2 = q - 1024; int e = q2 >> 4, ch = q2 & 15;
        int idx = bd[min(m0 + e, M - 1)];
        *(ushort8*)(&rows[e][128 + ch * 8]) = *(const ushort8*)(h2b + (size_t)idx * 128 + ch * 8);
      } else {
        int q2 = q - 2048; int e = q2 >> 2, ch = q2 & 3;
        int eg = min(m0 + e, M - 1);
        *(ushort8*)(&rows[e][256 + ch * 8]) = *(const ushort8*)(featb + (size_t)eg * 32 + ch * 8);
      }
    }
    if (tid < 64) outs[tid] = 0.f;
    __syncthreads();

    f32x4 acc[4][2];
    #pragma unroll
    for (int ms = 0; ms < 4; ++ms) { acc[ms][0] = (f32x4)0.f; acc[ms][1] = (f32x4)0.f; }
    #pragma unroll
    for (int kt = 0; kt < 9; ++kt) {
      bf16x8 af[4];
      #pragma unroll
      for (int ms = 0; ms < 4; ++ms)
        af[ms] = __builtin_bit_cast(bf16x8,
            *(const ushort8*)(&rows[ms * 16 + l4][kt * 32 + lg * 8]));
      #pragma unroll
      for (int ms = 0; ms < 4; ++ms) {
        acc[ms][0] = __builtin_amdgcn_mfma_f32_16x16x32_bf16(af[ms], bfrag[kt][0], acc[ms][0], 0, 0, 0);
        acc[ms][1] = __builtin_amdgcn_mfma_f32_16x16x32_bf16(af[ms], bfrag[kt][1], acc[ms][1], 0, 0, 0);
      }
    }
    #pragma unroll
    for (int ms = 0; ms < 4; ++ms) {
      #pragma unroll
      for (int r = 0; r < 4; ++r) {
        float z0 = fmaxf(acc[ms][0][r] + b0, 0.f);
        float z1 = fmaxf(acc[ms][1][r] + b1, 0.f);
        float v = z0 * w20 + z1 * w21;
        v += __shfl_xor(v, 1); v += __shfl_xor(v, 2);
        v += __shfl_xor(v, 4); v += __shfl_xor(v, 8);
        if (l4 == 0) atomicAdd(&outs[ms * 16 + lg * 4 + r], v);
      }
    }
    __syncthreads();
    if (tid < 64 && m0 + tid < M) out[m0 + tid] = outs[tid] + bc2v;
  }
}

// ---------------- launcher ----------------

extern "C" void kernel_launch(void* const* d_in, const int* in_sizes, int n_in,
                              void* d_out, int out_size, void* d_ws, size_t ws_size,
                              hipStream_t stream) {
  const float* x    = (const float*)d_in[0];
  const int*   ei   = (const int*)d_in[1];
  const int*   bei  = (const int*)d_in[2];
  const float* feat = (const float*)d_in[3];
  const float* W1l  = (const float*)d_in[4];
  const float* b1   = (const float*)d_in[5];
  const float* W1r  = (const float*)d_in[6];
  const float* W2l  = (const float*)d_in[7];
  const float* b2   = (const float*)d_in[8];
  const float* W2r  = (const float*)d_in[9];
  const float* Wc1  = (const float*)d_in[10];
  const float* bc1  = (const float*)d_in[11];
  const float* Wc2  = (const float*)d_in[12];
  const float* bc2  = (const float*)d_in[13];
  float* out = (float*)d_out;

  const int E  = in_sizes[1] / 2;   // 800000
  const int EB = in_sizes[2] / 2;   // 200000
  const int* src = ei;
  const int* dst = ei + E;
  const int* bs = bei;
  const int* bd = bei + EB;

  char* ws = (char*)d_ws;
  int*      cnt    = (int*)(ws + 0);                   // 200KB
  int*      offs   = (int*)(ws + (256u << 10));
  int*      cursor = (int*)(ws + (512u << 10));
  int*      bsum   = (int*)(ws + (768u << 10));
  int*      bpre   = (int*)(ws + (772u << 10));
  int*      nbr    = (int*)(ws + (1u  << 20));         // 3.2MB
  ushort_t* xb     = (ushort_t*)(ws + (8ull  << 20));  // 12.8MB
  ushort_t* aggb   = (ushort_t*)(ws + (24ull << 20));  // 12.8MB
  ushort_t* h1b    = (ushort_t*)(ws + (40ull << 20));  // 12.8MB
  ushort_t* h2b    = (ushort_t*)(ws + (56ull << 20));  // 12.8MB
  ushort_t* featb  = (ushort_t*)(ws + (72ull << 20));  // 12.8MB
  ushort_t* wt1    = (ushort_t*)(ws + (88ull << 20));  // 64KB
  ushort_t* wt2    = (ushort_t*)(ws + (88ull << 20) + (128u << 10));
  ushort_t* wtc    = (ushort_t*)(ws + (88ull << 20) + (256u << 10));

  hipMemsetAsync(cnt, 0, N_NODES * sizeof(int), stream);

  const int eb = (E + 255) / 256;
  const int nsb = (N_NODES + 255) / 256;   // 196 scan blocks
  k_prep<<<12900, 256, 0, stream>>>(x, xb, feat, featb, W1l, W1r, wt1, W2l, W2r, wt2, Wc1, wtc);
  k_hist<<<eb, 256, 0, stream>>>(dst, cnt, E);
  k_scan1<<<nsb, 256, 0, stream>>>(cnt, bsum, N_NODES);
  k_scan2<<<1, 256, 0, stream>>>(bsum, bpre, nsb, offs, N_NODES);
  k_scan3<<<nsb, 256, 0, stream>>>(cnt, bpre, offs, cursor, N_NODES);
  k_fill<<<eb, 256, 0, stream>>>(src, dst, cursor, nbr, E);

  // layer 1
  k_agg<<<2048, 256, 0, stream>>>(xb, offs, nbr, aggb, N_NODES);
  k_linear_mfma<<<782, 256, 0, stream>>>(aggb, xb, wt1, b1, h1b, N_NODES);
  // layer 2
  k_agg<<<2048, 256, 0, stream>>>(h1b, offs, nbr, aggb, N_NODES);
  k_linear_mfma<<<782, 256, 0, stream>>>(aggb, h1b, wt2, b2, h2b, N_NODES);
  // classifier
  k_cls_mfma<<<1024, 256, 0, stream>>>(h2b, bs, bd, featb, wtc, bc1, Wc2, bc2, out, EB);
}

// Round 5
// 255.532 us; speedup vs baseline: 4.5059x; 1.0726x over previous
//
#include <hip/hip_runtime.h>

#define N_NODES 50000

typedef unsigned short ushort_t;
typedef unsigned int uint_t;
typedef ushort_t ushort8 __attribute__((ext_vector_type(8)));
typedef __bf16 bf16x8 __attribute__((ext_vector_type(8)));
typedef float f32x4 __attribute__((ext_vector_type(4)));

__device__ inline ushort_t f2bf(float f) {
  union { float f; uint_t u; } v; v.f = f;
  uint_t u = v.u;
  uint_t r = (u + 0x7fffu + ((u >> 16) & 1u)) >> 16;  // RNE
  return (ushort_t)r;
}
__device__ inline uint_t pack2bf(float a, float b) {
  return (uint_t)f2bf(a) | ((uint_t)f2bf(b) << 16);
}
__device__ inline float bfup(ushort_t u) {
  union { uint_t u; float f; } v; v.u = (uint_t)u << 16; return v.f;
}

// ---------------- CSR build ----------------

__global__ void k_hist(const int* __restrict__ dst, int* __restrict__ cnt, int E) {
  int t = blockIdx.x * blockDim.x + threadIdx.x;
  if (t < E) atomicAdd(&cnt[dst[t]], 1);
}

__global__ void k_scan1(const int* __restrict__ cnt, int* __restrict__ bsum, int n) {
  __shared__ int s[256];
  int t = blockIdx.x * 256 + threadIdx.x;
  int v = (t < n) ? cnt[t] : 0;
  s[threadIdx.x] = v;
  __syncthreads();
  for (int d = 128; d; d >>= 1) {
    if (threadIdx.x < d) s[threadIdx.x] += s[threadIdx.x + d];
    __syncthreads();
  }
  if (threadIdx.x == 0) bsum[blockIdx.x] = s[0];
}

__global__ void k_scan2(const int* __restrict__ bsum, int* __restrict__ bpre,
                        int nb, int* __restrict__ offs, int n) {
  __shared__ int s[256];
  int tid = threadIdx.x;
  int v = (tid < nb) ? bsum[tid] : 0;
  s[tid] = v;
  __syncthreads();
  for (int d = 1; d < 256; d <<= 1) {
    int u = (tid >= d) ? s[tid - d] : 0;
    __syncthreads();
    s[tid] += u;
    __syncthreads();
  }
  if (tid < nb) bpre[tid] = s[tid] - v;
  if (tid == nb - 1) offs[n] = s[tid];
}

__global__ void k_scan3(const int* __restrict__ cnt, const int* __restrict__ bpre,
                        int* __restrict__ offs, int* __restrict__ cursor, int n) {
  __shared__ int s[256];
  int tid = threadIdx.x;
  int t = blockIdx.x * 256 + tid;
  int v = (t < n) ? cnt[t] : 0;
  s[tid] = v;
  __syncthreads();
  for (int d = 1; d < 256; d <<= 1) {
    int u = (tid >= d) ? s[tid - d] : 0;
    __syncthreads();
    s[tid] += u;
    __syncthreads();
  }
  if (t < n) {
    int ex = bpre[blockIdx.x] + s[tid] - v;
    offs[t] = ex; cursor[t] = ex;
  }
}

__global__ void k_fill(const int* __restrict__ src, const int* __restrict__ dst,
                       int* __restrict__ cursor, int* __restrict__ nbr, int E) {
  int t = blockIdx.x * blockDim.x + threadIdx.x;
  if (t < E) {
    int p = atomicAdd(&cursor[dst[t]], 1);
    nbr[p] = src[t];
  }
}

// ---------------- prep: x,feat -> bf16; weights -> bf16 transposed [col][k] ----------------

__global__ void k_prep(const float* __restrict__ x, ushort_t* __restrict__ xb,
                       const float* __restrict__ feat, ushort_t* __restrict__ featb,
                       const float* __restrict__ W1l, const float* __restrict__ W1r,
                       ushort_t* __restrict__ wt1,
                       const float* __restrict__ W2l, const float* __restrict__ W2r,
                       ushort_t* __restrict__ wt2,
                       const float* __restrict__ Wc1, ushort_t* __restrict__ wtc) {
  int bid = blockIdx.x, tid = threadIdx.x;
  if (bid < 6250) {                      // x: 6.4M elems as 1.6M float4
    int t = bid * 256 + tid;
    float4 v = *(const float4*)(x + (size_t)t * 4);
    uint2 p; p.x = pack2bf(v.x, v.y); p.y = pack2bf(v.z, v.w);
    *(uint2*)(xb + (size_t)t * 4) = p;
  } else if (bid < 12500) {              // feat: 6.4M elems
    int t = (bid - 6250) * 256 + tid;
    float4 v = *(const float4*)(feat + (size_t)t * 4);
    uint2 p; p.x = pack2bf(v.x, v.y); p.y = pack2bf(v.z, v.w);
    *(uint2*)(featb + (size_t)t * 4) = p;
  } else {                               // weight transposes
    int t = (bid - 12500) * 256 + tid;
    if (t < 32768) {
      int c = t >> 8, k = t & 255;
      wt1[t] = f2bf(k < 128 ? W1l[k * 128 + c] : W1r[(k - 128) * 128 + c]);
    } else if (t < 65536) {
      int t2 = t - 32768; int c = t2 >> 8, k = t2 & 255;
      wt2[t2] = f2bf(k < 128 ? W2l[k * 128 + c] : W2r[(k - 128) * 128 + c]);
    } else if (t < 65536 + 36864) {
      int t3 = t - 65536; int c = t3 / 288, k = t3 % 288;
      wtc[t3] = f2bf(Wc1[k * 128 + c]);
    }
  }
}

// ---------------- mean aggregation: 4 neighbor rows per step, 16B/lane ----------------
// lane = g*16 + l16; group g reads neighbor j+g, dims l16*8..l16*8+7.

__global__ void k_agg(const ushort_t* __restrict__ xb, const int* __restrict__ offs,
                      const int* __restrict__ nbr, ushort_t* __restrict__ aggb, int n) {
  const int lane = threadIdx.x & 63;
  const int g = lane >> 4;
  const int l16 = lane & 15;
  const int w = (int)((blockIdx.x * blockDim.x + threadIdx.x) >> 6);
  const int nw = (int)((gridDim.x * blockDim.x) >> 6);
  for (int node = w; node < n; node += nw) {
    const int beg = offs[node], end = offs[node + 1];
    float a0[8], a1[8];
    #pragma unroll
    for (int i = 0; i < 8; ++i) { a0[i] = 0.f; a1[i] = 0.f; }
    int j = beg;
    for (; j + 8 <= end; j += 8) {
      int s0 = nbr[j + g];
      int s1 = nbr[j + 4 + g];
      ushort8 v0 = *(const ushort8*)(xb + (size_t)s0 * 128 + l16 * 8);
      ushort8 v1 = *(const ushort8*)(xb + (size_t)s1 * 128 + l16 * 8);
      #pragma unroll
      for (int i = 0; i < 8; ++i) { a0[i] += bfup(v0[i]); a1[i] += bfup(v1[i]); }
    }
    if (j + 4 <= end) {
      int s0 = nbr[j + g];
      ushort8 v0 = *(const ushort8*)(xb + (size_t)s0 * 128 + l16 * 8);
      #pragma unroll
      for (int i = 0; i < 8; ++i) a0[i] += bfup(v0[i]);
      j += 4;
    }
    int rem = end - j;                 // 0..3
    if (rem > 0) {
      int s0 = nbr[j + min(g, rem - 1)];
      ushort8 v0 = *(const ushort8*)(xb + (size_t)s0 * 128 + l16 * 8);
      float m = (g < rem) ? 1.f : 0.f;
      #pragma unroll
      for (int i = 0; i < 8; ++i) a1[i] += m * bfup(v0[i]);
    }
    float inv = 1.0f / (float)max(end - beg, 1);
    ushort8 o;
    #pragma unroll
    for (int i = 0; i < 8; ++i) {
      float t = a0[i] + a1[i];
      t += __shfl_xor(t, 16);
      t += __shfl_xor(t, 32);
      o[i] = f2bf(t * inv);
    }
    if (g == 0)
      *(ushort8*)(aggb + (size_t)node * 128 + l16 * 8) = o;
  }
}

// ---------------- SAGE linear via bf16 MFMA ----------------

__global__ __launch_bounds__(256)
void k_linear_mfma(const ushort_t* __restrict__ aggb, const ushort_t* __restrict__ xinb,
                   const ushort_t* __restrict__ wt, const float* __restrict__ bias,
                   ushort_t* __restrict__ houtb, int M) {
  __shared__ ushort_t rows[64][258];
  const int tid = threadIdx.x;
  const int lane = tid & 63;
  const int w = tid >> 6;
  const int l4 = lane & 15, lg = lane >> 4;

  bf16x8 bfrag[8][2];
  #pragma unroll
  for (int kt = 0; kt < 8; ++kt)
    #pragma unroll
    for (int ct = 0; ct < 2; ++ct) {
      int col = w * 32 + ct * 16 + l4;
      bfrag[kt][ct] = __builtin_bit_cast(bf16x8,
          *(const ushort8*)(wt + (size_t)col * 256 + kt * 32 + lg * 8));
    }
  const int col0 = w * 32 + l4, col1 = col0 + 16;
  const float b0 = bias[col0], b1 = bias[col1];

  const int niter = (M + 63) >> 6;
  for (int it = blockIdx.x; it < niter; it += gridDim.x) {
    const int m0 = it << 6;
    __syncthreads();
    #pragma unroll
    for (int c = 0; c < 8; ++c) {
      int q = c * 256 + tid;
      int e = q >> 5, ch = q & 31;
      int rg = min(m0 + e, M - 1);
      const ushort_t* p = (ch < 16) ? (aggb + (size_t)rg * 128 + ch * 8)
                                    : (xinb + (size_t)rg * 128 + (ch - 16) * 8);
      *(ushort8*)(&rows[e][ch * 8]) = *(const ushort8*)p;
    }
    __syncthreads();

    f32x4 acc[4][2];
    #pragma unroll
    for (int ms = 0; ms < 4; ++ms) { acc[ms][0] = (f32x4)0.f; acc[ms][1] = (f32x4)0.f; }
    #pragma unroll
    for (int kt = 0; kt < 8; ++kt) {
      bf16x8 af[4];
      #pragma unroll
      for (int ms = 0; ms < 4; ++ms)
        af[ms] = __builtin_bit_cast(bf16x8,
            *(const ushort8*)(&rows[ms * 16 + l4][kt * 32 + lg * 8]));
      #pragma unroll
      for (int ms = 0; ms < 4; ++ms) {
        acc[ms][0] = __builtin_amdgcn_mfma_f32_16x16x32_bf16(af[ms], bfrag[kt][0], acc[ms][0], 0, 0, 0);
        acc[ms][1] = __builtin_amdgcn_mfma_f32_16x16x32_bf16(af[ms], bfrag[kt][1], acc[ms][1], 0, 0, 0);
      }
    }
    #pragma unroll
    for (int ms = 0; ms < 4; ++ms)
      #pragma unroll
      for (int r = 0; r < 4; ++r) {
        int rg = m0 + ms * 16 + lg * 4 + r;
        if (rg < M) {
          houtb[(size_t)rg * 128 + col0] = f2bf(fmaxf(acc[ms][0][r] + b0, 0.f));
          houtb[(size_t)rg * 128 + col1] = f2bf(fmaxf(acc[ms][1][r] + b1, 0.f));
        }
      }
  }
}

// ---------------- classifier via bf16 MFMA, reg-staged async pipeline ----------------

__device__ __forceinline__ void cls_load(int m0, int tid, const int* __restrict__ bs,
                                         const int* __restrict__ bd,
                                         const ushort_t* __restrict__ h2b,
                                         const ushort_t* __restrict__ featb,
                                         int M, ushort8* r) {
  #pragma unroll
  for (int c = 0; c < 9; ++c) {
    int q = c * 256 + tid;
    if (q < 1024) {
      int e = q >> 4, ch = q & 15;
      int idx = bs[min(m0 + e, M - 1)];
      r[c] = *(const ushort8*)(h2b + (size_t)idx * 128 + ch * 8);
    } else if (q < 2048) {
      int q2 = q - 1024; int e = q2 >> 4, ch = q2 & 15;
      int idx = bd[min(m0 + e, M - 1)];
      r[c] = *(const ushort8*)(h2b + (size_t)idx * 128 + ch * 8);
    } else {
      int q2 = q - 2048; int e = q2 >> 2, ch = q2 & 3;
      int eg = min(m0 + e, M - 1);
      r[c] = *(const ushort8*)(featb + (size_t)eg * 32 + ch * 8);
    }
  }
}

__device__ __forceinline__ void cls_store(int tid, const ushort8* r, ushort_t (*rows)[296]) {
  #pragma unroll
  for (int c = 0; c < 9; ++c) {
    int q = c * 256 + tid;
    if (q < 1024) {
      int e = q >> 4, ch = q & 15;
      *(ushort8*)(&rows[e][ch * 8]) = r[c];
    } else if (q < 2048) {
      int q2 = q - 1024; int e = q2 >> 4, ch = q2 & 15;
      *(ushort8*)(&rows[e][128 + ch * 8]) = r[c];
    } else {
      int q2 = q - 2048; int e = q2 >> 2, ch = q2 & 3;
      *(ushort8*)(&rows[e][256 + ch * 8]) = r[c];
    }
  }
}

__global__ __launch_bounds__(256)
void k_cls_mfma(const ushort_t* __restrict__ h2b, const int* __restrict__ bs,
                const int* __restrict__ bd, const ushort_t* __restrict__ featb,
                const ushort_t* __restrict__ wt, const float* __restrict__ bc1,
                const float* __restrict__ Wc2, const float* __restrict__ bc2,
                float* __restrict__ out, int M) {
  __shared__ ushort_t rows[64][296];
  __shared__ float outs[64];
  const int tid = threadIdx.x;
  const int lane = tid & 63;
  const int w = tid >> 6;
  const int l4 = lane & 15, lg = lane >> 4;

  bf16x8 bfrag[9][2];
  #pragma unroll
  for (int kt = 0; kt < 9; ++kt)
    #pragma unroll
    for (int ct = 0; ct < 2; ++ct) {
      int col = w * 32 + ct * 16 + l4;
      bfrag[kt][ct] = __builtin_bit_cast(bf16x8,
          *(const ushort8*)(wt + (size_t)col * 288 + kt * 32 + lg * 8));
    }
  const int col0 = w * 32 + l4, col1 = col0 + 16;
  const float b0 = bc1[col0], b1 = bc1[col1];
  const float w20 = Wc2[col0], w21 = Wc2[col1];
  const float bc2v = bc2[0];

  const int niter = (M + 63) >> 6;
  const int gstep = gridDim.x;
  int it = blockIdx.x;
  ushort8 r[9];
  if (it < niter) cls_load(it << 6, tid, bs, bd, h2b, featb, M, r);

  while (it < niter) {
    const int m0 = it << 6;
    __syncthreads();                       // prev compute + outs consumption done
    cls_store(tid, r, rows);
    if (tid < 64) outs[tid] = 0.f;
    __syncthreads();                       // staging visible
    const int itn = it + gstep;
    if (itn < niter) cls_load(itn << 6, tid, bs, bd, h2b, featb, M, r);  // async prefetch

    f32x4 acc[4][2];
    #pragma unroll
    for (int ms = 0; ms < 4; ++ms) { acc[ms][0] = (f32x4)0.f; acc[ms][1] = (f32x4)0.f; }
    #pragma unroll
    for (int kt = 0; kt < 9; ++kt) {
      bf16x8 af[4];
      #pragma unroll
      for (int ms = 0; ms < 4; ++ms)
        af[ms] = __builtin_bit_cast(bf16x8,
            *(const ushort8*)(&rows[ms * 16 + l4][kt * 32 + lg * 8]));
      #pragma unroll
      for (int ms = 0; ms < 4; ++ms) {
        acc[ms][0] = __builtin_amdgcn_mfma_f32_16x16x32_bf16(af[ms], bfrag[kt][0], acc[ms][0], 0, 0, 0);
        acc[ms][1] = __builtin_amdgcn_mfma_f32_16x16x32_bf16(af[ms], bfrag[kt][1], acc[ms][1], 0, 0, 0);
      }
    }
    #pragma unroll
    for (int ms = 0; ms < 4; ++ms) {
      #pragma unroll
      for (int rr = 0; rr < 4; ++rr) {
        float z0 = fmaxf(acc[ms][0][rr] + b0, 0.f);
        float z1 = fmaxf(acc[ms][1][rr] + b1, 0.f);
        float v = z0 * w20 + z1 * w21;
        v += __shfl_xor(v, 1); v += __shfl_xor(v, 2);
        v += __shfl_xor(v, 4); v += __shfl_xor(v, 8);
        if (l4 == 0) atomicAdd(&outs[ms * 16 + lg * 4 + rr], v);
      }
    }
    __syncthreads();                       // outs complete
    if (tid < 64 && m0 + tid < M) out[m0 + tid] = outs[tid] + bc2v;
    it = itn;
  }
}

// ---------------- launcher ----------------

extern "C" void kernel_launch(void* const* d_in, const int* in_sizes, int n_in,
                              void* d_out, int out_size, void* d_ws, size_t ws_size,
                              hipStream_t stream) {
  const float* x    = (const float*)d_in[0];
  const int*   ei   = (const int*)d_in[1];
  const int*   bei  = (const int*)d_in[2];
  const float* feat = (const float*)d_in[3];
  const float* W1l  = (const float*)d_in[4];
  const float* b1   = (const float*)d_in[5];
  const float* W1r  = (const float*)d_in[6];
  const float* W2l  = (const float*)d_in[7];
  const float* b2   = (const float*)d_in[8];
  const float* W2r  = (const float*)d_in[9];
  const float* Wc1  = (const float*)d_in[10];
  const float* bc1  = (const float*)d_in[11];
  const float* Wc2  = (const float*)d_in[12];
  const float* bc2  = (const float*)d_in[13];
  float* out = (float*)d_out;

  const int E  = in_sizes[1] / 2;   // 800000
  const int EB = in_sizes[2] / 2;   // 200000
  const int* src = ei;
  const int* dst = ei + E;
  const int* bs = bei;
  const int* bd = bei + EB;

  char* ws = (char*)d_ws;
  int*      cnt    = (int*)(ws + 0);                   // 200KB
  int*      offs   = (int*)(ws + (256u << 10));
  int*      cursor = (int*)(ws + (512u << 10));
  int*      bsum   = (int*)(ws + (768u << 10));
  int*      bpre   = (int*)(ws + (772u << 10));
  int*      nbr    = (int*)(ws + (1u  << 20));         // 3.2MB
  ushort_t* xb     = (ushort_t*)(ws + (8ull  << 20));  // 12.8MB
  ushort_t* aggb   = (ushort_t*)(ws + (24ull << 20));  // 12.8MB
  ushort_t* h1b    = (ushort_t*)(ws + (40ull << 20));  // 12.8MB
  ushort_t* h2b    = (ushort_t*)(ws + (56ull << 20));  // 12.8MB
  ushort_t* featb  = (ushort_t*)(ws + (72ull << 20));  // 12.8MB
  ushort_t* wt1    = (ushort_t*)(ws + (88ull << 20));  // 64KB
  ushort_t* wt2    = (ushort_t*)(ws + (88ull << 20) + (128u << 10));
  ushort_t* wtc    = (ushort_t*)(ws + (88ull << 20) + (256u << 10));

  hipMemsetAsync(cnt, 0, N_NODES * sizeof(int), stream);

  const int eb = (E + 255) / 256;
  const int nsb = (N_NODES + 255) / 256;   // 196 scan blocks
  k_prep<<<12900, 256, 0, stream>>>(x, xb, feat, featb, W1l, W1r, wt1, W2l, W2r, wt2, Wc1, wtc);
  k_hist<<<eb, 256, 0, stream>>>(dst, cnt, E);
  k_scan1<<<nsb, 256, 0, stream>>>(cnt, bsum, N_NODES);
  k_scan2<<<1, 256, 0, stream>>>(bsum, bpre, nsb, offs, N_NODES);
  k_scan3<<<nsb, 256, 0, stream>>>(cnt, bpre, offs, cursor, N_NODES);
  k_fill<<<eb, 256, 0, stream>>>(src, dst, cursor, nbr, E);

  // layer 1
  k_agg<<<2048, 256, 0, stream>>>(xb, offs, nbr, aggb, N_NODES);
  k_linear_mfma<<<782, 256, 0, stream>>>(aggb, xb, wt1, b1, h1b, N_NODES);
  // layer 2
  k_agg<<<2048, 256, 0, stream>>>(h1b, offs, nbr, aggb, N_NODES);
  k_linear_mfma<<<782, 256, 0, stream>>>(aggb, h1b, wt2, b2, h2b, N_NODES);
  // classifier
  k_cls_mfma<<<768, 256, 0, stream>>>(h2b, bs, bd, featb, wtc, bc1, Wc2, bc2, out, EB);
}